// Round 1
// baseline (244.029 us; speedup 1.0000x reference)
//
#include <hip/hip_runtime.h>
#include <stdint.h>

#define NIMG 8
#define CIN 64
#define HH 128
#define WWID 128
#define L (HH*WWID)        // 16384
#define COUT 128
#define PATCH 576          // CIN*9
#define TBL 65536
#define OFFV 32768
#define CAP 4096
#define SPB 4              // slots per gemm block

// ---------------- kernel 1: channel sum (f64) ----------------
__global__ void csum_kernel(const float* __restrict__ fmap, double* __restrict__ csum) {
    int idx = blockIdx.x * blockDim.x + threadIdx.x;     // n*L + hw
    if (idx >= NIMG * L) return;
    int n  = idx >> 14;
    int hw = idx & (L - 1);
    const float* p = fmap + (size_t)n * CIN * L + hw;
    double s = 0.0;
    #pragma unroll
    for (int c = 0; c < CIN; ++c) s += (double)p[(size_t)c * L];
    csum[idx] = s;
}

// ---------------- kernel 2: 3x3 window sum -> q, atomicMin first index ----------------
__global__ void quant_kernel(const double* __restrict__ csum, int* __restrict__ qarr,
                             unsigned int* __restrict__ firstIdx) {
    int idx = blockIdx.x * blockDim.x + threadIdx.x;
    if (idx >= NIMG * L) return;
    int n  = idx >> 14;
    int hw = idx & (L - 1);
    int h = hw >> 7, w = hw & 127;
    const double* base = csum + (size_t)n * L;
    double s = 0.0;
    #pragma unroll
    for (int ki = -1; ki <= 1; ++ki) {
        int hh = h + ki;
        if (hh < 0 || hh >= HH) continue;
        #pragma unroll
        for (int kj = -1; kj <= 1; ++kj) {
            int ww = w + kj;
            if (ww < 0 || ww >= WWID) continue;
            s += base[hh * WWID + ww];
        }
    }
    double avg = s / 576.0;
    int q = (int)(avg * 1000.0);          // trunc toward zero, like .astype(int32)
    qarr[idx] = q;
    int v = q + OFFV;
    v = v < 0 ? 0 : (v > TBL - 1 ? TBL - 1 : v);
    atomicMin(&firstIdx[(size_t)n * TBL + v], (unsigned int)hw);
}

// ---------------- kernel 3: compact unique values -> slots ----------------
__global__ void compact_kernel(const unsigned int* __restrict__ firstIdx,
                               int* __restrict__ slotTab, unsigned int* __restrict__ uniqJ,
                               int* __restrict__ count) {
    int idx = blockIdx.x * blockDim.x + threadIdx.x;
    if (idx >= NIMG * TBL) return;
    unsigned int fi = firstIdx[idx];
    if (fi != 0xFFFFFFFFu) {
        int n = idx >> 16;
        int s = atomicAdd(&count[n], 1);
        slotTab[idx] = s;
        if (s < CAP) uniqJ[n * CAP + s] = fi;
    }
}

// ---------------- kernel 4: per-position slot map ----------------
__global__ void slmap_kernel(const int* __restrict__ qarr, const int* __restrict__ slotTab,
                             int* __restrict__ sl) {
    int idx = blockIdx.x * blockDim.x + threadIdx.x;
    if (idx >= NIMG * L) return;
    int n = idx >> 14;
    int q = qarr[idx];
    int v = q + OFFV;
    v = v < 0 ? 0 : (v > TBL - 1 ? TBL - 1 : v);
    sl[idx] = slotTab[(size_t)n * TBL + v];
}

// ---------------- kernel 5: tiny GEMM on unique representative patches ----------------
__global__ __launch_bounds__(128) void gemm_kernel(const float* __restrict__ fmap,
                            const float* __restrict__ weight, const float* __restrict__ bias,
                            const unsigned int* __restrict__ uniqJ, const int* __restrict__ count,
                            float* __restrict__ R) {
    int n  = blockIdx.y;
    int s0 = blockIdx.x * SPB;
    int cnt = count[n];
    int cntc = cnt < CAP ? cnt : CAP;
    if (s0 >= cntc) return;
    __shared__ float patch[SPB][PATCH];
    __shared__ float Wt[128][33];        // +1 pad: (tid*33+kk)%32 spreads banks
    int tid = threadIdx.x;

    // cooperative patch gather for up to SPB slots
    for (int i = tid; i < SPB * PATCH; i += 128) {
        int si = i / PATCH, p = i - si * PATCH;
        float v = 0.f;
        int s = s0 + si;
        if (s < cntc) {
            unsigned int j = uniqJ[n * CAP + s];
            int h0 = j >> 7, w0 = j & 127;
            int c = p / 9, r = p - c * 9;
            int hh = h0 + r / 3 - 1;
            int ww = w0 + (r % 3) - 1;
            if (hh >= 0 && hh < HH && ww >= 0 && ww < WWID)
                v = fmap[((size_t)n * CIN + c) * L + hh * WWID + ww];
        }
        patch[si][p] = v;
    }
    __syncthreads();

    float acc[SPB] = {0.f, 0.f, 0.f, 0.f};
    for (int k0 = 0; k0 < PATCH; k0 += 32) {
        for (int i = tid; i < 128 * 32; i += 128) {
            int row = i >> 5, col = i & 31;
            Wt[row][col] = weight[row * PATCH + k0 + col];
        }
        __syncthreads();
        #pragma unroll
        for (int kk = 0; kk < 32; ++kk) {
            float wv = Wt[tid][kk];
            acc[0] += wv * patch[0][k0 + kk];
            acc[1] += wv * patch[1][k0 + kk];
            acc[2] += wv * patch[2][k0 + kk];
            acc[3] += wv * patch[3][k0 + kk];
        }
        __syncthreads();
    }
    float b = bias[tid];
    #pragma unroll
    for (int i = 0; i < SPB; ++i) {
        int s = s0 + i;
        if (s < cntc) R[((size_t)n * COUT + tid) * CAP + s] = acc[i] + b;
    }
}

// ---------------- kernel 6: scatter results to output ----------------
__global__ void scatter_kernel(const float* __restrict__ weight, const float* __restrict__ bias,
                               const float* __restrict__ fmap,
                               const int* __restrict__ sl, const int* __restrict__ qarr,
                               const unsigned int* __restrict__ firstIdx,
                               const float* __restrict__ R, float* __restrict__ out) {
    int idx = blockIdx.x * blockDim.x + threadIdx.x;   // n, o, l
    if (idx >= NIMG * COUT * L) return;
    int l = idx & (L - 1);
    int o = (idx >> 14) & 127;
    int n = idx >> 21;
    int s = sl[n * L + l];
    float val;
    if (s < CAP) {
        val = R[((size_t)n * COUT + o) * CAP + s];
    } else {
        // cold fallback (formally correct; never triggered for this input)
        int q = qarr[n * L + l];
        int v = q + OFFV;
        v = v < 0 ? 0 : (v > TBL - 1 ? TBL - 1 : v);
        unsigned int j = firstIdx[(size_t)n * TBL + v];
        int h0 = j >> 7, w0 = j & 127;
        const float* wrow = weight + (size_t)o * PATCH;
        float acc = 0.f;
        for (int c = 0; c < CIN; ++c)
            for (int r = 0; r < 9; ++r) {
                int hh = h0 + r / 3 - 1;
                int ww = w0 + (r % 3) - 1;
                float pv = (hh >= 0 && hh < HH && ww >= 0 && ww < WWID)
                           ? fmap[((size_t)n * CIN + c) * L + hh * WWID + ww] : 0.f;
                acc += wrow[c * 9 + r] * pv;
            }
        val = acc + bias[o];
    }
    out[idx] = val;
}

extern "C" void kernel_launch(void* const* d_in, const int* in_sizes, int n_in,
                              void* d_out, int out_size, void* d_ws, size_t ws_size,
                              hipStream_t stream) {
    const float* fmap   = (const float*)d_in[0];
    const float* weight = (const float*)d_in[1];
    const float* bias   = (const float*)d_in[2];
    float* out = (float*)d_out;

    char* ws = (char*)d_ws;
    double*       csum     = (double*)ws;        ws += (size_t)NIMG * L * 8;       // 1 MB
    int*          qarr     = (int*)ws;           ws += (size_t)NIMG * L * 4;       // 0.5 MB
    unsigned int* firstIdx = (unsigned int*)ws;  ws += (size_t)NIMG * TBL * 4;     // 2 MB
    int*          slotTab  = (int*)ws;           ws += (size_t)NIMG * TBL * 4;     // 2 MB
    int*          sl       = (int*)ws;           ws += (size_t)NIMG * L * 4;       // 0.5 MB
    unsigned int* uniqJ    = (unsigned int*)ws;  ws += (size_t)NIMG * CAP * 4;     // 128 KB
    int*          count    = (int*)ws;           ws += 128;
    float*        R        = (float*)ws;         ws += (size_t)NIMG * COUT * CAP * 4; // 16 MB

    hipMemsetAsync(firstIdx, 0xFF, (size_t)NIMG * TBL * 4, stream);
    hipMemsetAsync(count, 0, 128, stream);

    int nl = NIMG * L;
    csum_kernel <<<(nl + 255) / 256, 256, 0, stream>>>(fmap, csum);
    quant_kernel<<<(nl + 255) / 256, 256, 0, stream>>>(csum, qarr, firstIdx);
    compact_kernel<<<(NIMG * TBL + 255) / 256, 256, 0, stream>>>(firstIdx, slotTab, uniqJ, count);
    slmap_kernel<<<(nl + 255) / 256, 256, 0, stream>>>(qarr, slotTab, sl);
    dim3 gg(CAP / SPB, NIMG);
    gemm_kernel<<<gg, 128, 0, stream>>>(fmap, weight, bias, uniqJ, count, R);
    scatter_kernel<<<(NIMG * COUT * L + 255) / 256, 256, 0, stream>>>(weight, bias, fmap, sl, qarr, firstIdx, R, out);
}

// Round 2
// 213.790 us; speedup vs baseline: 1.1414x; 1.1414x over previous
//
#include <hip/hip_runtime.h>
#include <stdint.h>

#define NIMG 8
#define CIN 64
#define HH 128
#define WWID 128
#define L (HH*WWID)        // 16384
#define COUT 128
#define PATCH 576          // CIN*9
#define TBL 65536
#define OFFV 32768
#define CAP 4096
#define SPB 8              // slots per gemm block

// ---------------- kernel 1: channel sum (f64), 4 outputs/thread ----------------
__global__ __launch_bounds__(256) void csum_kernel(const float* __restrict__ fmap,
                                                   double* __restrict__ csum) {
    int idx = blockIdx.x * blockDim.x + threadIdx.x;   // over NIMG*L/4
    if (idx >= NIMG * L / 4) return;
    int n   = idx >> 12;                 // L/4 = 4096 per image
    int hw4 = (idx & (L / 4 - 1)) << 2;
    const float* p = fmap + (size_t)n * CIN * L + hw4;
    double s0 = 0, s1 = 0, s2 = 0, s3 = 0;
    #pragma unroll 8
    for (int c = 0; c < CIN; ++c) {
        float4 v = *(const float4*)(p + (size_t)c * L);
        s0 += (double)v.x; s1 += (double)v.y; s2 += (double)v.z; s3 += (double)v.w;
    }
    double* q = csum + (size_t)n * L + hw4;
    q[0] = s0; q[1] = s1; q[2] = s2; q[3] = s3;
}

// ---------------- kernel 2: 3x3 window sum -> q, atomicMin first index ----------------
__global__ void quant_kernel(const double* __restrict__ csum, int* __restrict__ qarr,
                             unsigned int* __restrict__ firstIdx) {
    int idx = blockIdx.x * blockDim.x + threadIdx.x;
    if (idx >= NIMG * L) return;
    int n  = idx >> 14;
    int hw = idx & (L - 1);
    int h = hw >> 7, w = hw & 127;
    const double* base = csum + (size_t)n * L;
    double s = 0.0;
    #pragma unroll
    for (int ki = -1; ki <= 1; ++ki) {
        int hh = h + ki;
        if (hh < 0 || hh >= HH) continue;
        #pragma unroll
        for (int kj = -1; kj <= 1; ++kj) {
            int ww = w + kj;
            if (ww < 0 || ww >= WWID) continue;
            s += base[hh * WWID + ww];
        }
    }
    double avg = s / 576.0;
    int q = (int)(avg * 1000.0);          // trunc toward zero, like .astype(int32)
    qarr[idx] = q;
    int v = q + OFFV;
    v = v < 0 ? 0 : (v > TBL - 1 ? TBL - 1 : v);
    atomicMin(&firstIdx[(size_t)n * TBL + v], (unsigned int)hw);
}

// ---------------- kernel 3: compact unique values -> slots ----------------
__global__ void compact_kernel(const unsigned int* __restrict__ firstIdx,
                               int* __restrict__ slotTab, unsigned int* __restrict__ uniqJ,
                               int* __restrict__ count) {
    int idx = blockIdx.x * blockDim.x + threadIdx.x;
    if (idx >= NIMG * TBL) return;
    unsigned int fi = firstIdx[idx];
    if (fi != 0xFFFFFFFFu) {
        int n = idx >> 16;
        int s = atomicAdd(&count[n], 1);
        slotTab[idx] = s;
        if (s < CAP) uniqJ[n * CAP + s] = fi;
    }
}

// ---------------- kernel 4: GEMM on unique representative patches ----------------
// 256 threads: o = tid&127 (output channel), half = tid>>7 (K-half of 288).
// Weight rows streamed per-thread from global (L2-resident). Patch reads are
// wave-uniform float4 LDS broadcasts (conflict-free).
__global__ __launch_bounds__(256) void gemm_kernel(const float* __restrict__ fmap,
                            const float* __restrict__ weight, const float* __restrict__ bias,
                            const unsigned int* __restrict__ uniqJ, const int* __restrict__ count,
                            float* __restrict__ R) {
    int n  = blockIdx.y;
    int s0 = blockIdx.x * SPB;
    int cnt = count[n];
    if (cnt > CAP) cnt = CAP;
    if (s0 >= cnt) return;

    __shared__ float patch[SPB][PATCH];        // 18432 B
    __shared__ float part[COUT][SPB + 1];      // 4608 B, +1 pad: conflict-light
    int tid = threadIdx.x;

    // cooperative patch gather (18 independent scattered loads per thread)
    #pragma unroll
    for (int i = tid; i < SPB * PATCH; i += 256) {
        int si = i / PATCH, p = i - si * PATCH;
        float v = 0.f;
        int s = s0 + si;
        if (s < cnt) {
            unsigned int j = uniqJ[n * CAP + s];
            int h0 = j >> 7, w0 = j & 127;
            int c = p / 9, r = p - c * 9;
            int hh = h0 + r / 3 - 1;
            int ww = w0 + (r % 3) - 1;
            if (hh >= 0 && hh < HH && ww >= 0 && ww < WWID)
                v = fmap[((size_t)n * CIN + c) * L + hh * WWID + ww];
        }
        patch[si][p] = v;
    }
    __syncthreads();

    int o     = tid & 127;
    int half  = tid >> 7;
    int kbase = half * (PATCH / 2);            // 0 or 288, wave-uniform
    const float* wrow = weight + (size_t)o * PATCH + kbase;

    float acc[SPB];
    #pragma unroll
    for (int i = 0; i < SPB; ++i) acc[i] = 0.f;

    #pragma unroll 4
    for (int kk = 0; kk < PATCH / 2; kk += 4) {
        float4 wv = *(const float4*)(wrow + kk);
        #pragma unroll
        for (int i = 0; i < SPB; ++i) {
            float4 pv = *(const float4*)(&patch[i][kbase + kk]);   // uniform -> broadcast
            acc[i] += wv.x * pv.x + wv.y * pv.y + wv.z * pv.z + wv.w * pv.w;
        }
    }

    if (half == 1) {
        #pragma unroll
        for (int i = 0; i < SPB; ++i) part[o][i] = acc[i];
    }
    __syncthreads();
    if (half == 0) {
        float b = bias[o];
        float* Rrow = R + ((size_t)n * COUT + o) * CAP;
        #pragma unroll
        for (int i = 0; i < SPB; ++i) {
            int s = s0 + i;
            if (s < cnt) Rrow[s] = acc[i] + part[o][i] + b;
        }
    }
}

// ---------------- kernel 5: scatter results to output (float4 writes) ----------------
__global__ __launch_bounds__(256) void scatter_kernel(const float* __restrict__ weight,
                               const float* __restrict__ bias, const float* __restrict__ fmap,
                               const int* __restrict__ qarr, const int* __restrict__ slotTab,
                               const unsigned int* __restrict__ firstIdx,
                               const float* __restrict__ R, float* __restrict__ out) {
    int idx = blockIdx.x * blockDim.x + threadIdx.x;   // over NIMG*COUT*L/4
    if (idx >= NIMG * COUT * L / 4) return;
    int l4 = (idx & (L / 4 - 1)) << 2;     // 12 bits
    int o  = (idx >> 12) & 127;
    int n  = idx >> 19;

    int4 q4 = *(const int4*)(qarr + (size_t)n * L + l4);
    const int* st = slotTab + (size_t)n * TBL;
    const float* Rrow = R + ((size_t)n * COUT + o) * CAP;

    float4 val;
    float* vp = (float*)&val;
    const int* qp = (const int*)&q4;
    #pragma unroll
    for (int e = 0; e < 4; ++e) {
        int q = qp[e];
        int v = q + OFFV;
        v = v < 0 ? 0 : (v > TBL - 1 ? TBL - 1 : v);
        int s = st[v];
        if (s < CAP) {
            vp[e] = Rrow[s];
        } else {
            // cold fallback (formally correct; never triggered for this input)
            unsigned int j = firstIdx[(size_t)n * TBL + v];
            int h0 = j >> 7, w0 = j & 127;
            const float* wr = weight + (size_t)o * PATCH;
            float acc = 0.f;
            for (int c = 0; c < CIN; ++c)
                for (int r = 0; r < 9; ++r) {
                    int hh = h0 + r / 3 - 1;
                    int ww = w0 + (r % 3) - 1;
                    float pv = (hh >= 0 && hh < HH && ww >= 0 && ww < WWID)
                               ? fmap[((size_t)n * CIN + c) * L + hh * WWID + ww] : 0.f;
                    acc += wr[c * 9 + r] * pv;
                }
            vp[e] = acc + bias[o];
        }
    }
    *(float4*)(out + ((size_t)n * COUT + o) * L + l4) = val;
}

extern "C" void kernel_launch(void* const* d_in, const int* in_sizes, int n_in,
                              void* d_out, int out_size, void* d_ws, size_t ws_size,
                              hipStream_t stream) {
    const float* fmap   = (const float*)d_in[0];
    const float* weight = (const float*)d_in[1];
    const float* bias   = (const float*)d_in[2];
    float* out = (float*)d_out;

    char* ws = (char*)d_ws;
    double*       csum     = (double*)ws;        ws += (size_t)NIMG * L * 8;       // 1 MB
    int*          qarr     = (int*)ws;           ws += (size_t)NIMG * L * 4;       // 0.5 MB
    unsigned int* firstIdx = (unsigned int*)ws;  ws += (size_t)NIMG * TBL * 4;     // 2 MB
    int*          slotTab  = (int*)ws;           ws += (size_t)NIMG * TBL * 4;     // 2 MB
    unsigned int* uniqJ    = (unsigned int*)ws;  ws += (size_t)NIMG * CAP * 4;     // 128 KB
    int*          count    = (int*)ws;           ws += 128;
    float*        R        = (float*)ws;         ws += (size_t)NIMG * COUT * CAP * 4; // 16 MB

    hipMemsetAsync(firstIdx, 0xFF, (size_t)NIMG * TBL * 4, stream);
    hipMemsetAsync(count, 0, 128, stream);

    int nl4 = NIMG * L / 4;
    csum_kernel <<<(nl4 + 255) / 256, 256, 0, stream>>>(fmap, csum);
    quant_kernel<<<(NIMG * L + 255) / 256, 256, 0, stream>>>(csum, qarr, firstIdx);
    compact_kernel<<<(NIMG * TBL + 255) / 256, 256, 0, stream>>>(firstIdx, slotTab, uniqJ, count);
    dim3 gg(CAP / SPB, NIMG);
    gemm_kernel<<<gg, 256, 0, stream>>>(fmap, weight, bias, uniqJ, count, R);
    int no4 = NIMG * COUT * L / 4;
    scatter_kernel<<<(no4 + 255) / 256, 256, 0, stream>>>(weight, bias, fmap, qarr, slotTab, firstIdx, R, out);
}

// Round 4
// 203.816 us; speedup vs baseline: 1.1973x; 1.0489x over previous
//
#include <hip/hip_runtime.h>
#include <stdint.h>

#define NIMG 8
#define CIN 64
#define HH 128
#define WWID 128
#define L (HH*WWID)        // 16384
#define COUT 128
#define PATCH 576          // CIN*9
#define TBL 65536
#define OFFV 32768
#define CAP 4096
#define SPB 8              // slots per gemm block

// ---------------- kernel 0: weight transpose W[128][576] -> Wt[576][128] ----------------
__global__ __launch_bounds__(256) void wtrans_kernel(const float* __restrict__ W,
                                                     float* __restrict__ Wt) {
    int idx = blockIdx.x * 256 + threadIdx.x;
    if (idx >= COUT * PATCH) return;
    int k = idx >> 7, o = idx & 127;
    Wt[idx] = W[o * PATCH + k];
}

// ---------------- kernel 1: fused channel-sum + 3x3 window sum + quantize ----------------
// 16x16 output tile per block; 18x18 f64 channel-sum halo in LDS.
// Summation order identical to previous rounds: channels ascending, then ki,kj ascending.
__global__ __launch_bounds__(256) void csq_kernel(const float* __restrict__ fmap,
                                                  int* __restrict__ qarr,
                                                  unsigned int* __restrict__ firstIdx) {
    int bid  = blockIdx.x;            // n*64 + tile
    int n    = bid >> 6;
    int tile = bid & 63;
    int h0 = (tile >> 3) << 4;
    int w0 = (tile & 7) << 4;
    __shared__ double cs[18 * 18];
    int tid = threadIdx.x;
    const float* fb = fmap + (size_t)n * CIN * L;

    for (int p = tid; p < 324; p += 256) {
        int th = p / 18, tw = p - th * 18;
        int h = h0 + th - 1, w = w0 + tw - 1;
        double s = 0.0;
        if (h >= 0 && h < HH && w >= 0 && w < WWID) {
            const float* q = fb + h * WWID + w;
            #pragma unroll 8
            for (int c = 0; c < CIN; ++c) s += (double)q[(size_t)c * L];
        }
        cs[p] = s;
    }
    __syncthreads();

    int th = tid >> 4, tw = tid & 15;
    double s = 0.0;
    #pragma unroll
    for (int ki = 0; ki < 3; ++ki)
        #pragma unroll
        for (int kj = 0; kj < 3; ++kj)
            s += cs[(th + ki) * 18 + tw + kj];
    double avg = s / 576.0;
    int q = (int)(avg * 1000.0);      // trunc toward zero
    int hw = (h0 + th) * WWID + (w0 + tw);
    qarr[n * L + hw] = q;
    int v = q + OFFV;
    v = v < 0 ? 0 : (v > TBL - 1 ? TBL - 1 : v);
    atomicMin(&firstIdx[(size_t)n * TBL + v], (unsigned int)hw);
}

// ---------------- kernel 2: compact unique values -> slots ----------------
__global__ void compact_kernel(const unsigned int* __restrict__ firstIdx,
                               int* __restrict__ slotTab, unsigned int* __restrict__ uniqJ,
                               int* __restrict__ count) {
    int idx = blockIdx.x * blockDim.x + threadIdx.x;
    if (idx >= NIMG * TBL) return;
    unsigned int fi = firstIdx[idx];
    if (fi != 0xFFFFFFFFu) {
        int n = idx >> 16;
        int s = atomicAdd(&count[n], 1);
        slotTab[idx] = s;
        if (s < CAP) uniqJ[n * CAP + s] = fi;
    }
}

// ---------------- kernel 3: GEMM on unique representative patches ----------------
// 256 threads: op = tid&63 (o-pair: outputs 2*op, 2*op+1), kq = tid>>6 (K-quarter of 144).
// Weight reads coalesced from Wt[k][o] (float2/lane, 512B/wave-inst).
// Patch reads: wave-uniform ds_read_b128 broadcasts. 4-way K reduce via LDS.
__global__ __launch_bounds__(256) void gemm_kernel(const float* __restrict__ fmap,
                            const float* __restrict__ Wt, const float* __restrict__ bias,
                            const unsigned int* __restrict__ uniqJ, const int* __restrict__ count,
                            float* __restrict__ R) {
    int n  = blockIdx.y;
    int s0 = blockIdx.x * SPB;
    int cnt = count[n];
    if (cnt > CAP) cnt = CAP;
    if (s0 >= cnt) return;

    __shared__ float patch[SPB][PATCH];          // 18432 B
    __shared__ float part[3][64][2][SPB];        // 12288 B
    int tid = threadIdx.x;

    // cooperative patch gather (18 scattered scalar loads per thread)
    #pragma unroll
    for (int i = tid; i < SPB * PATCH; i += 256) {
        int si = i / PATCH, p = i - si * PATCH;
        float v = 0.f;
        int s = s0 + si;
        if (s < cnt) {
            unsigned int j = uniqJ[n * CAP + s];
            int hj = j >> 7, wj = j & 127;
            int c = p / 9, r = p - c * 9;
            int hh = hj + r / 3 - 1;
            int ww = wj + (r % 3) - 1;
            if (hh >= 0 && hh < HH && ww >= 0 && ww < WWID)
                v = fmap[((size_t)n * CIN + c) * L + hh * WWID + ww];
        }
        patch[si][p] = v;
    }
    __syncthreads();

    int op = tid & 63;
    int kq = tid >> 6;
    int kbase = kq * (PATCH / 4);                // 0,144,288,432 — wave-uniform

    float acc[2][SPB];
    #pragma unroll
    for (int j = 0; j < 2; ++j)
        #pragma unroll
        for (int i = 0; i < SPB; ++i) acc[j][i] = 0.f;

    const float* wp = Wt + (size_t)kbase * COUT + op * 2;
    #pragma unroll 2
    for (int kk = 0; kk < PATCH / 4; kk += 4) {
        float2 w0 = *(const float2*)(wp + (kk + 0) * COUT);
        float2 w1 = *(const float2*)(wp + (kk + 1) * COUT);
        float2 w2 = *(const float2*)(wp + (kk + 2) * COUT);
        float2 w3 = *(const float2*)(wp + (kk + 3) * COUT);
        #pragma unroll
        for (int i = 0; i < SPB; ++i) {
            float4 pv = *(const float4*)(&patch[i][kbase + kk]);   // uniform -> broadcast
            acc[0][i] += w0.x * pv.x + w1.x * pv.y + w2.x * pv.z + w3.x * pv.w;
            acc[1][i] += w0.y * pv.x + w1.y * pv.y + w2.y * pv.z + w3.y * pv.w;
        }
    }

    if (kq) {
        #pragma unroll
        for (int j = 0; j < 2; ++j)
            #pragma unroll
            for (int i = 0; i < SPB; ++i) part[kq - 1][op][j][i] = acc[j][i];
    }
    __syncthreads();
    if (kq == 0) {
        #pragma unroll
        for (int j = 0; j < 2; ++j) {
            int o = op * 2 + j;
            float b = bias[o];
            float* Rrow = R + ((size_t)n * COUT + o) * CAP;
            #pragma unroll
            for (int i = 0; i < SPB; ++i) {
                int s = s0 + i;
                if (s < cnt)
                    Rrow[s] = acc[j][i] + part[0][op][j][i] + part[1][op][j][i]
                            + part[2][op][j][i] + b;
            }
        }
    }
}

// ---------------- kernel 4: scatter results to output (float4 writes) ----------------
__global__ __launch_bounds__(256) void scatter_kernel(const float* __restrict__ weight,
                               const float* __restrict__ bias, const float* __restrict__ fmap,
                               const int* __restrict__ qarr, const int* __restrict__ slotTab,
                               const unsigned int* __restrict__ firstIdx,
                               const float* __restrict__ R, float* __restrict__ out) {
    int idx = blockIdx.x * blockDim.x + threadIdx.x;   // over NIMG*COUT*L/4
    if (idx >= NIMG * COUT * L / 4) return;
    int l4 = (idx & (L / 4 - 1)) << 2;
    int o  = (idx >> 12) & 127;
    int n  = idx >> 19;

    int4 q4 = *(const int4*)(qarr + (size_t)n * L + l4);
    const int* st = slotTab + (size_t)n * TBL;
    const float* Rrow = R + ((size_t)n * COUT + o) * CAP;

    float4 val;
    float* vp = (float*)&val;
    const int* qp = (const int*)&q4;
    #pragma unroll
    for (int e = 0; e < 4; ++e) {
        int q = qp[e];
        int v = q + OFFV;
        v = v < 0 ? 0 : (v > TBL - 1 ? TBL - 1 : v);
        int s = st[v];
        if (s < CAP) {
            vp[e] = Rrow[s];
        } else {
            // cold fallback (formally correct; never triggered for this input)
            unsigned int j = firstIdx[(size_t)n * TBL + v];
            int h0 = j >> 7, w0 = j & 127;
            const float* wr = weight + (size_t)o * PATCH;
            float acc = 0.f;
            for (int c = 0; c < CIN; ++c)
                for (int r = 0; r < 9; ++r) {
                    int hh = h0 + r / 3 - 1;
                    int ww = w0 + (r % 3) - 1;
                    float pv = (hh >= 0 && hh < HH && ww >= 0 && ww < WWID)
                               ? fmap[((size_t)n * CIN + c) * L + hh * WWID + ww] : 0.f;
                    acc += wr[c * 9 + r] * pv;
                }
            vp[e] = acc + bias[o];
        }
    }
    *(float4*)(out + ((size_t)n * COUT + o) * L + l4) = val;
}

extern "C" void kernel_launch(void* const* d_in, const int* in_sizes, int n_in,
                              void* d_out, int out_size, void* d_ws, size_t ws_size,
                              hipStream_t stream) {
    const float* fmap   = (const float*)d_in[0];
    const float* weight = (const float*)d_in[1];
    const float* bias   = (const float*)d_in[2];
    float* out = (float*)d_out;

    char* ws = (char*)d_ws;
    int*          qarr     = (int*)ws;           ws += (size_t)NIMG * L * 4;       // 0.5 MB
    unsigned int* firstIdx = (unsigned int*)ws;  ws += (size_t)NIMG * TBL * 4;     // 2 MB
    int*          slotTab  = (int*)ws;           ws += (size_t)NIMG * TBL * 4;     // 2 MB
    unsigned int* uniqJ    = (unsigned int*)ws;  ws += (size_t)NIMG * CAP * 4;     // 128 KB
    int*          count    = (int*)ws;           ws += 128;
    float*        Wt       = (float*)ws;         ws += (size_t)COUT * PATCH * 4;   // 288 KB
    float*        R        = (float*)ws;         ws += (size_t)NIMG * COUT * CAP * 4; // 16 MB

    hipMemsetAsync(firstIdx, 0xFF, (size_t)NIMG * TBL * 4, stream);
    hipMemsetAsync(count, 0, 128, stream);

    wtrans_kernel<<<(COUT * PATCH + 255) / 256, 256, 0, stream>>>(weight, Wt);
    csq_kernel<<<NIMG * 64, 256, 0, stream>>>(fmap, qarr, firstIdx);
    compact_kernel<<<(NIMG * TBL + 255) / 256, 256, 0, stream>>>(firstIdx, slotTab, uniqJ, count);
    dim3 gg(CAP / SPB, NIMG);
    gemm_kernel<<<gg, 256, 0, stream>>>(fmap, Wt, bias, uniqJ, count, R);
    int no4 = NIMG * COUT * L / 4;
    scatter_kernel<<<(no4 + 255) / 256, 256, 0, stream>>>(weight, bias, fmap, qarr, slotTab, firstIdx, R, out);
}